// Round 4
// baseline (121.099 us; speedup 1.0000x reference)
//
#include <hip/hip_runtime.h>
#include <hip/hip_bf16.h>

#define BB 8
#define NN 4096
#define FF 128
#define DD 64
#define NB (BB*NN)           // 32768 rows total
#define CHK 128              // i-chunk size for rank kernel B1
#define NCH (NN/CHK)         // 32 rank chunks per batch
#define CSZ 16               // stats chunk size
#define NC16 (NN/CSZ)        // 256 stats chunks per batch
#define CH 72                // channel stride in stats tables (65 used: 64 ch + Z)

// workspace byte offsets
#define OFF_H     0                                     // float [NB][64]   8 MB
#define OFF_S1    (OFF_H    + (size_t)NB*DD*4)
#define OFF_S2    (OFF_S1   + (size_t)NB*4)
#define OFF_S2S   (OFF_S2   + (size_t)NB*4)
#define OFF_PERM  (OFF_S2S  + (size_t)NB*4)
#define OFF_WPOS  (OFF_PERM + (size_t)NB*4)
#define OFF_WNEG  (OFF_WPOS + (size_t)NB*4)
#define OFF_CT16  (OFF_WNEG + (size_t)NB*4)             // double [B][256][2][72] 2.36 MB
#define OFF_CTS   (OFF_CT16 + (size_t)BB*NC16*2*CH*8)   // double [B][257][2][72] 2.37 MB
#define OFF_PRANK (OFF_CTS  + (size_t)BB*(NC16+1)*2*CH*8) // u16 [32][B][4096]  2 MB

// monotone float->u32 map (IEEE total order for non-NaN)
__device__ __forceinline__ unsigned int fkey(float f) {
  unsigned int u = __float_as_uint(f);
  return (u & 0x80000000u) ? ~u : (u | 0x80000000u);
}

// ---------------- Kernel A: h = x @ W^T ; s1 = h.a1 ; s2 = h.a2 ----------------
__global__ __launch_bounds__(256) void gat_kA(const float* __restrict__ x,
                                              const float* __restrict__ W,
                                              const float* __restrict__ a,
                                              float* __restrict__ h,
                                              float* __restrict__ s1,
                                              float* __restrict__ s2) {
  __shared__ float xs[64][FF];
  const int tid  = threadIdx.x;
  const int lane = tid & 63;
  const int wave = tid >> 6;
  const long long rowbase = (long long)blockIdx.x * 64;

  const float4* x4  = (const float4*)(x + rowbase * FF);
  float4*       xs4 = (float4*)&xs[0][0];
#pragma unroll
  for (int i = 0; i < 8; ++i) xs4[tid + i * 256] = x4[tid + i * 256];

  float4 wreg[32];
  const float4* W4 = (const float4*)(W + lane * FF);
#pragma unroll
  for (int j = 0; j < 32; ++j) wreg[j] = W4[j];
  const float a1d = a[lane];
  const float a2d = a[DD + lane];
  __syncthreads();

  for (int r = wave * 16; r < wave * 16 + 16; ++r) {
    const float4* xr = (const float4*)&xs[r][0];
    float4 acc = {0.f, 0.f, 0.f, 0.f};
#pragma unroll
    for (int j = 0; j < 32; ++j) {
      float4 xv = xr[j];
      acc.x += xv.x * wreg[j].x;
      acc.y += xv.y * wreg[j].y;
      acc.z += xv.z * wreg[j].z;
      acc.w += xv.w * wreg[j].w;
    }
    float hd = (acc.x + acc.y) + (acc.z + acc.w);
    const long long row = rowbase + r;
    h[row * DD + lane] = hd;

    float p1 = hd * a1d, p2 = hd * a2d;
#pragma unroll
    for (int o = 32; o; o >>= 1) { p1 += __shfl_xor(p1, o); p2 += __shfl_xor(p2, o); }
    if (lane == 0) { s1[row] = p1; s2[row] = p2; }
  }
}

// ---------------- Kernel B1: partial ranks, register-blocked ----------------
__global__ __launch_bounds__(256) void gat_kB1(const float* __restrict__ s2,
                                               unsigned short* __restrict__ prank) {
  __shared__ unsigned long long ks[CHK];
  const int c = blockIdx.x, b = blockIdx.y, tid = threadIdx.x;
  const float* s2b = s2 + (size_t)b * NN;

  if (tid < CHK) {
    const int ig = c * CHK + tid;
    ks[tid] = ((unsigned long long)fkey(s2b[ig]) << 12) | (unsigned)ig;
  }

  unsigned long long kj[16];
  int rank[16];
#pragma unroll
  for (int t = 0; t < 16; ++t) {
    const int j = tid + 256 * t;
    kj[t] = ((unsigned long long)fkey(s2b[j]) << 12) | (unsigned)j;
    rank[t] = 0;
  }
  __syncthreads();

#pragma unroll 4
  for (int i = 0; i < CHK; ++i) {
    const unsigned long long ki = ks[i];
#pragma unroll
    for (int t = 0; t < 16; ++t) rank[t] += (ki < kj[t]) ? 1 : 0;
  }

  unsigned short* pr = prank + ((size_t)c * BB + b) * NN;
#pragma unroll
  for (int t = 0; t < 16; ++t) pr[tid + 256 * t] = (unsigned short)rank[t];
}

// ---------------- Kernel B2: sum partials, batch max, scatter + exp tables ------
__global__ __launch_bounds__(256) void gat_kB2(const float* __restrict__ s2,
                                               const unsigned short* __restrict__ prank,
                                               float* __restrict__ s2s,
                                               int* __restrict__ perm,
                                               float* __restrict__ wpos,
                                               float* __restrict__ wneg) {
  __shared__ float red[4];
  const int b = blockIdx.y, tid = threadIdx.x;
  const int j = blockIdx.x * 256 + tid;
  const float* s2b = s2 + (size_t)b * NN;

  float mx = -3.4e38f;
  for (int i = tid; i < NN; i += 256) mx = fmaxf(mx, s2b[i]);
#pragma unroll
  for (int o = 32; o; o >>= 1) mx = fmaxf(mx, __shfl_xor(mx, o));
  if ((tid & 63) == 0) red[tid >> 6] = mx;
  __syncthreads();
  mx = fmaxf(fmaxf(red[0], red[1]), fmaxf(red[2], red[3]));

  int rank = 0;
#pragma unroll 8
  for (int c = 0; c < NCH; ++c) rank += prank[((size_t)c * BB + b) * NN + j];

  const float key = s2b[j];
  const size_t o = (size_t)b * NN + rank;
  s2s[o]  = key;
  perm[o] = j;
  wpos[o] = expf(key - mx);           // <= 1
  wneg[o] = expf(0.2f * (key - mx));  // <= 1
}

// ---------------- Kernel C: 16-element chunk partial sums, fp64 ----------------
// grid (256 chunks, 8 batches) x 64; coalesced [b][c][fam][72] stores
__global__ __launch_bounds__(64) void gat_kC(const float* __restrict__ h,
                                             const int* __restrict__ perm,
                                             const float* __restrict__ wpos,
                                             const float* __restrict__ wneg,
                                             double* __restrict__ CT16) {
  const int c = blockIdx.x, b = blockIdx.y, d = threadIdx.x;
  const int base = b * NN + c * CSZ;
  double ap = 0, an = 0, zp = 0, zn = 0;
#pragma unroll
  for (int s = 0; s < CSZ; ++s) {
    const int j  = base + s;
    const int pj = perm[j];
    const float hv = h[((size_t)b * NN + pj) * DD + d];
    const float wp = wpos[j], wn = wneg[j];
    ap += (double)wp * hv; an += (double)wn * hv;
    zp += wp;              zn += wn;
  }
  double* o = CT16 + ((size_t)(b * NC16 + c) * 2) * CH;
  o[0 * CH + d] = an;   // fam0 = negative-branch (wneg)
  o[1 * CH + d] = ap;   // fam1 = positive-branch (wpos)
  if (d == 0) { o[0 * CH + 64] = zn; o[1 * CH + 64] = zp; }
}

// ---------------- Kernel D: exclusive scan CT16 -> CTS (separate buffer) --------
// grid (8 batches) x 256: thread = fam*128 + ch; coalesced loads/stores
__global__ __launch_bounds__(256) void gat_kD(const double* __restrict__ CT16,
                                              double* __restrict__ CTS) {
  const int b = blockIdx.x, t = threadIdx.x;
  const int fam = t >> 7, ch = t & 127;
  if (ch > 64) return;
  double off = 0;
#pragma unroll 4
  for (int c = 0; c < NC16; ++c) {
    CTS[(((size_t)b * (NC16 + 1) + c) * 2 + fam) * CH + ch] = off;
    off += CT16[(((size_t)b * NC16 + c) * 2 + fam) * CH + ch];
  }
  CTS[(((size_t)b * (NC16 + 1) + NC16) * 2 + fam) * CH + ch] = off;
}

// ---------------- Kernel F: binary search + chunk refine + combine + ELU --------
// one wave per output row; lane = channel d
__global__ __launch_bounds__(256) void gat_kF(const float* __restrict__ s1,
                                              const float* __restrict__ s2s,
                                              const int* __restrict__ perm,
                                              const float* __restrict__ wpos,
                                              const float* __restrict__ wneg,
                                              const float* __restrict__ h,
                                              const double* __restrict__ CTS,
                                              float* __restrict__ out) {
  const int tid = threadIdx.x, lane = tid & 63, wv = tid >> 6;
  const long long row = (long long)blockIdx.x * 4 + wv;   // 0..32767
  const int b = (int)(row >> 12);
  const float* s2b = s2s + (size_t)b * NN;

  const float s1i = s1[row];
  const float c1  = s2b[NN - 1];
  const float t   = -s1i;

  int lo = 0, hi = NN;
  while (lo < hi) { int mid = (lo + hi) >> 1; if (s2b[mid] <= t) lo = mid + 1; else hi = mid; }
  const int k = lo;
  const int c16 = k >> 4;

  const double* base0 = CTS + ((size_t)b * (NC16 + 1)) * 2 * CH;
  const double* r0 = base0 + (size_t)c16 * 2 * CH;          // fam0 prefix row
  const double* r1 = r0 + CH;                               // fam1 prefix row
  const double* tt = base0 + (size_t)NC16 * 2 * CH + CH;    // fam1 total row

  double pre  = r0[lane];
  double p1   = r1[lane];
  double Zpre = r0[64];
  double Z1   = r1[64];
  const double tot = tt[lane];
  const double Zt  = tt[64];

  // refine: add elements [c16*16, k) of the sorted order
  for (int j = (c16 << 4); j < k; ++j) {
    const int pj = perm[b * NN + j];
    const float hv = h[((size_t)b * NN + pj) * DD + lane];
    const float wp = wpos[b * NN + j], wn = wneg[b * NN + j];
    pre += (double)wn * hv; p1 += (double)wp * hv;
    Zpre += wn;             Z1 += wp;
  }

  const float suf_d = (float)(tot - p1);
  const float Zsuf  = (float)(Zt - Z1);

  const float z = s1i + c1;
  const float m = z >= 0.f ? z : 0.2f * z;
  const float A  = expf(z - m);
  const float Bn = expf(0.2f * z - m);

  const float num = A * suf_d + Bn * (float)pre;
  const float Z   = A * Zsuf  + Bn * (float)Zpre;
  const float hp  = num / Z;
  out[row * DD + lane] = hp > 0.f ? hp : expm1f(hp);
}

extern "C" void kernel_launch(void* const* d_in, const int* in_sizes, int n_in,
                              void* d_out, int out_size, void* d_ws, size_t ws_size,
                              hipStream_t stream) {
  const float* x = (const float*)d_in[0];
  const float* W = (const float*)d_in[1];
  const float* a = (const float*)d_in[2];
  float* out = (float*)d_out;

  char* ws = (char*)d_ws;
  float*  h    = (float*)(ws + OFF_H);
  float*  s1   = (float*)(ws + OFF_S1);
  float*  s2   = (float*)(ws + OFF_S2);
  float*  s2s  = (float*)(ws + OFF_S2S);
  int*    perm = (int*)  (ws + OFF_PERM);
  float*  wpos = (float*)(ws + OFF_WPOS);
  float*  wneg = (float*)(ws + OFF_WNEG);
  double* CT16 = (double*)(ws + OFF_CT16);
  double* CTS  = (double*)(ws + OFF_CTS);
  unsigned short* prank = (unsigned short*)(ws + OFF_PRANK);

  gat_kA<<<NB / 64, 256, 0, stream>>>(x, W, a, h, s1, s2);
  gat_kB1<<<dim3(NCH, BB), 256, 0, stream>>>(s2, prank);
  gat_kB2<<<dim3(NN / 256, BB), 256, 0, stream>>>(s2, prank, s2s, perm, wpos, wneg);
  gat_kC<<<dim3(NC16, BB), 64, 0, stream>>>(h, perm, wpos, wneg, CT16);
  gat_kD<<<BB, 256, 0, stream>>>(CT16, CTS);
  gat_kF<<<NB / 4, 256, 0, stream>>>(s1, s2s, perm, wpos, wneg, h, CTS, out);
}

// Round 5
// 101.794 us; speedup vs baseline: 1.1896x; 1.1896x over previous
//
#include <hip/hip_runtime.h>
#include <hip/hip_bf16.h>

#define BB 8
#define NN 4096
#define FF 128
#define DD 64
#define NB (BB*NN)           // 32768 rows total
#define CHK 128              // i-chunk size for rank kernel B1
#define NCH (NN/CHK)         // 32 rank chunks per batch
#define CSZ 16               // stats chunk size
#define NC16 (NN/CSZ)        // 256 stats chunks per batch
#define CH 72                // channel stride in stats tables (65 used: 64 ch + Z)

// workspace byte offsets
#define OFF_H     0                                     // float [NB][64]   8 MB
#define OFF_S1    (OFF_H    + (size_t)NB*DD*4)
#define OFF_S2    (OFF_S1   + (size_t)NB*4)
#define OFF_S2S   (OFF_S2   + (size_t)NB*4)
#define OFF_PERM  (OFF_S2S  + (size_t)NB*4)
#define OFF_WPOS  (OFF_PERM + (size_t)NB*4)
#define OFF_WNEG  (OFF_WPOS + (size_t)NB*4)
#define OFF_CT16  (OFF_WNEG + (size_t)NB*4)             // double [B][256][2][72] 2.36 MB
#define OFF_CTS   (OFF_CT16 + (size_t)BB*NC16*2*CH*8)   // double [B][257][2][72] 2.37 MB
#define OFF_PRANK (OFF_CTS  + (size_t)BB*(NC16+1)*2*CH*8) // u16 [32][B][4096]  2 MB

// monotone float->u32 map (IEEE total order for non-NaN)
__device__ __forceinline__ unsigned int fkey(float f) {
  unsigned int u = __float_as_uint(f);
  return (u & 0x80000000u) ? ~u : (u | 0x80000000u);
}

// ---------------- Kernel A: h = x @ W^T ; s1 = h.a1 ; s2 = h.a2 ----------------
__global__ __launch_bounds__(256) void gat_kA(const float* __restrict__ x,
                                              const float* __restrict__ W,
                                              const float* __restrict__ a,
                                              float* __restrict__ h,
                                              float* __restrict__ s1,
                                              float* __restrict__ s2) {
  __shared__ float xs[64][FF];
  const int tid  = threadIdx.x;
  const int lane = tid & 63;
  const int wave = tid >> 6;
  const long long rowbase = (long long)blockIdx.x * 64;

  const float4* x4  = (const float4*)(x + rowbase * FF);
  float4*       xs4 = (float4*)&xs[0][0];
#pragma unroll
  for (int i = 0; i < 8; ++i) xs4[tid + i * 256] = x4[tid + i * 256];

  float4 wreg[32];
  const float4* W4 = (const float4*)(W + lane * FF);
#pragma unroll
  for (int j = 0; j < 32; ++j) wreg[j] = W4[j];
  const float a1d = a[lane];
  const float a2d = a[DD + lane];
  __syncthreads();

  for (int r = wave * 16; r < wave * 16 + 16; ++r) {
    const float4* xr = (const float4*)&xs[r][0];
    float4 acc = {0.f, 0.f, 0.f, 0.f};
#pragma unroll
    for (int j = 0; j < 32; ++j) {
      float4 xv = xr[j];
      acc.x += xv.x * wreg[j].x;
      acc.y += xv.y * wreg[j].y;
      acc.z += xv.z * wreg[j].z;
      acc.w += xv.w * wreg[j].w;
    }
    float hd = (acc.x + acc.y) + (acc.z + acc.w);
    const long long row = rowbase + r;
    h[row * DD + lane] = hd;

    float p1 = hd * a1d, p2 = hd * a2d;
#pragma unroll
    for (int o = 32; o; o >>= 1) { p1 += __shfl_xor(p1, o); p2 += __shfl_xor(p2, o); }
    if (lane == 0) { s1[row] = p1; s2[row] = p2; }
  }
}

// ---------------- Kernel B1: partial ranks, register-blocked ----------------
__global__ __launch_bounds__(256) void gat_kB1(const float* __restrict__ s2,
                                               unsigned short* __restrict__ prank) {
  __shared__ unsigned long long ks[CHK];
  const int c = blockIdx.x, b = blockIdx.y, tid = threadIdx.x;
  const float* s2b = s2 + (size_t)b * NN;

  if (tid < CHK) {
    const int ig = c * CHK + tid;
    ks[tid] = ((unsigned long long)fkey(s2b[ig]) << 12) | (unsigned)ig;
  }

  unsigned long long kj[16];
  int rank[16];
#pragma unroll
  for (int t = 0; t < 16; ++t) {
    const int j = tid + 256 * t;
    kj[t] = ((unsigned long long)fkey(s2b[j]) << 12) | (unsigned)j;
    rank[t] = 0;
  }
  __syncthreads();

#pragma unroll 4
  for (int i = 0; i < CHK; ++i) {
    const unsigned long long ki = ks[i];
#pragma unroll
    for (int t = 0; t < 16; ++t) rank[t] += (ki < kj[t]) ? 1 : 0;
  }

  unsigned short* pr = prank + ((size_t)c * BB + b) * NN;
#pragma unroll
  for (int t = 0; t < 16; ++t) pr[tid + 256 * t] = (unsigned short)rank[t];
}

// ---------------- Kernel B2: sum partials, batch max, scatter + exp tables ------
__global__ __launch_bounds__(256) void gat_kB2(const float* __restrict__ s2,
                                               const unsigned short* __restrict__ prank,
                                               float* __restrict__ s2s,
                                               int* __restrict__ perm,
                                               float* __restrict__ wpos,
                                               float* __restrict__ wneg) {
  __shared__ float red[4];
  const int b = blockIdx.y, tid = threadIdx.x;
  const int j = blockIdx.x * 256 + tid;
  const float* s2b = s2 + (size_t)b * NN;

  float mx = -3.4e38f;
  for (int i = tid; i < NN; i += 256) mx = fmaxf(mx, s2b[i]);
#pragma unroll
  for (int o = 32; o; o >>= 1) mx = fmaxf(mx, __shfl_xor(mx, o));
  if ((tid & 63) == 0) red[tid >> 6] = mx;
  __syncthreads();
  mx = fmaxf(fmaxf(red[0], red[1]), fmaxf(red[2], red[3]));

  int rank = 0;
#pragma unroll 8
  for (int c = 0; c < NCH; ++c) rank += prank[((size_t)c * BB + b) * NN + j];

  const float key = s2b[j];
  const size_t o = (size_t)b * NN + rank;
  s2s[o]  = key;
  perm[o] = j;
  wpos[o] = expf(key - mx);           // <= 1
  wneg[o] = expf(0.2f * (key - mx));  // <= 1
}

// ---------------- Kernel C: 16-element chunk partial sums, fp64 ----------------
__global__ __launch_bounds__(64) void gat_kC(const float* __restrict__ h,
                                             const int* __restrict__ perm,
                                             const float* __restrict__ wpos,
                                             const float* __restrict__ wneg,
                                             double* __restrict__ CT16) {
  const int c = blockIdx.x, b = blockIdx.y, d = threadIdx.x;
  const int base = b * NN + c * CSZ;
  double ap = 0, an = 0, zp = 0, zn = 0;
#pragma unroll
  for (int s = 0; s < CSZ; ++s) {
    const int j  = base + s;
    const int pj = perm[j];
    const float hv = h[((size_t)b * NN + pj) * DD + d];
    const float wp = wpos[j], wn = wneg[j];
    ap += (double)wp * hv; an += (double)wn * hv;
    zp += wp;              zn += wn;
  }
  double* o = CT16 + ((size_t)(b * NC16 + c) * 2) * CH;
  o[0 * CH + d] = an;   // fam0 = negative-branch (wneg)
  o[1 * CH + d] = ap;   // fam1 = positive-branch (wpos)
  if (d == 0) { o[0 * CH + 64] = zn; o[1 * CH + 64] = zp; }
}

// ---------------- Kernel D: exclusive scan CT16 -> CTS (separate buffer) --------
__global__ __launch_bounds__(256) void gat_kD(const double* __restrict__ CT16,
                                              double* __restrict__ CTS) {
  const int b = blockIdx.x, t = threadIdx.x;
  const int fam = t >> 7, ch = t & 127;
  if (ch > 64) return;
  double off = 0;
#pragma unroll 4
  for (int c = 0; c < NC16; ++c) {
    CTS[(((size_t)b * (NC16 + 1) + c) * 2 + fam) * CH + ch] = off;
    off += CT16[(((size_t)b * NC16 + c) * 2 + fam) * CH + ch];
  }
  CTS[(((size_t)b * (NC16 + 1) + NC16) * 2 + fam) * CH + ch] = off;
}

// ---------------- Kernel F: LDS keys + ballot search + chunk refine + ELU -------
// grid (256 row-groups, 8 batches) x 256; block stages its batch's sorted keys
// in LDS and computes 16 output rows (4 per wave). lane = channel d.
__global__ __launch_bounds__(256) void gat_kF(const float* __restrict__ s1,
                                              const float* __restrict__ s2s,
                                              const int* __restrict__ perm,
                                              const float* __restrict__ wpos,
                                              const float* __restrict__ wneg,
                                              const float* __restrict__ h,
                                              const double* __restrict__ CTS,
                                              float* __restrict__ out) {
  __shared__ float key[NN];      // 16 KB
  __shared__ float seglast[64];  // segment-last keys (conflict-free round 1)
  const int b = blockIdx.y;
  const int tid = threadIdx.x, lane = tid & 63, wv = tid >> 6;

  const float4* src = (const float4*)(s2s + (size_t)b * NN);
  float4* dst = (float4*)key;
#pragma unroll
  for (int i = 0; i < 4; ++i) dst[tid + 256 * i] = src[tid + 256 * i];
  __syncthreads();
  if (tid < 64) seglast[tid] = key[tid * 64 + 63];
  __syncthreads();

  const float c1 = key[NN - 1];
  const double* base0 = CTS + ((size_t)b * (NC16 + 1)) * 2 * CH;
  const double* tt = base0 + (size_t)NC16 * 2 * CH + CH;  // fam1 total row
  const double tot = tt[lane];
  const double Zt  = tt[64];
  const int bNN = b * NN;
  const float segl = seglast[lane];

  for (int r = 0; r < 4; ++r) {
    const int rowl = blockIdx.x * 16 + wv * 4 + r;
    const long long row = (long long)bNN + rowl;
    const float s1i = s1[row];
    const float t = -s1i;

    // 64-ary ballot search: k = #{j : key[j] <= t}
    unsigned long long m1 = __ballot(segl <= t);
    int seg = __popcll(m1); if (seg > 63) seg = 63;
    const float v2 = key[seg * 64 + lane];
    unsigned long long m2 = __ballot(v2 <= t);
    const int k = seg * 64 + __popcll(m2);
    const int c16 = k >> 4;

    const double* r0 = base0 + (size_t)c16 * 2 * CH;  // fam0 prefix row
    const double* r1 = r0 + CH;                       // fam1 prefix row
    double pre  = r0[lane];
    double p1v  = r1[lane];
    double Zpre = r0[64];
    double Z1   = r1[64];

    // refine: add sorted elements [c16*16, k)
    for (int j = (c16 << 4); j < k; ++j) {
      const int pj = perm[bNN + j];
      const float hv = h[((size_t)(bNN + pj)) * DD + lane];
      const float wp = wpos[bNN + j], wn = wneg[bNN + j];
      pre += (double)wn * hv; p1v += (double)wp * hv;
      Zpre += wn;             Z1 += wp;
    }

    const float suf_d = (float)(tot - p1v);
    const float Zsuf  = (float)(Zt - Z1);
    const float z = s1i + c1;
    const float m = z >= 0.f ? z : 0.2f * z;
    const float A  = expf(z - m);
    const float Bn = expf(0.2f * z - m);
    const float num = A * suf_d + Bn * (float)pre;
    const float Z   = A * Zsuf  + Bn * (float)Zpre;
    const float hp  = num / Z;
    out[row * DD + lane] = hp > 0.f ? hp : expm1f(hp);
  }
}

extern "C" void kernel_launch(void* const* d_in, const int* in_sizes, int n_in,
                              void* d_out, int out_size, void* d_ws, size_t ws_size,
                              hipStream_t stream) {
  const float* x = (const float*)d_in[0];
  const float* W = (const float*)d_in[1];
  const float* a = (const float*)d_in[2];
  float* out = (float*)d_out;

  char* ws = (char*)d_ws;
  float*  h    = (float*)(ws + OFF_H);
  float*  s1   = (float*)(ws + OFF_S1);
  float*  s2   = (float*)(ws + OFF_S2);
  float*  s2s  = (float*)(ws + OFF_S2S);
  int*    perm = (int*)  (ws + OFF_PERM);
  float*  wpos = (float*)(ws + OFF_WPOS);
  float*  wneg = (float*)(ws + OFF_WNEG);
  double* CT16 = (double*)(ws + OFF_CT16);
  double* CTS  = (double*)(ws + OFF_CTS);
  unsigned short* prank = (unsigned short*)(ws + OFF_PRANK);

  gat_kA<<<NB / 64, 256, 0, stream>>>(x, W, a, h, s1, s2);
  gat_kB1<<<dim3(NCH, BB), 256, 0, stream>>>(s2, prank);
  gat_kB2<<<dim3(NN / 256, BB), 256, 0, stream>>>(s2, prank, s2s, perm, wpos, wneg);
  gat_kC<<<dim3(NC16, BB), 64, 0, stream>>>(h, perm, wpos, wneg, CT16);
  gat_kD<<<BB, 256, 0, stream>>>(CT16, CTS);
  gat_kF<<<dim3(NN / 16, BB), 256, 0, stream>>>(s1, s2s, perm, wpos, wneg, h, CTS, out);
}

// Round 6
// 85.780 us; speedup vs baseline: 1.4117x; 1.1867x over previous
//
#include <hip/hip_runtime.h>
#include <hip/hip_bf16.h>

#define BB 8
#define NN 4096
#define FF 128
#define DD 64
#define NB (BB*NN)           // 32768 rows total
#define CHK 128              // i-chunk size for rank kernel B1
#define NCH (NN/CHK)         // 32 rank chunks per batch
#define CSZ 16               // stats chunk size
#define NC16 (NN/CSZ)        // 256 stats chunks per batch
#define CH 72                // channel stride in stats tables (65 used: 64 ch + Z)

// workspace byte offsets
#define OFF_H     0                                     // float [NB][64]   8 MB
#define OFF_S1    (OFF_H    + (size_t)NB*DD*4)
#define OFF_S2    (OFF_S1   + (size_t)NB*4)
#define OFF_S2S   (OFF_S2   + (size_t)NB*4)
#define OFF_PK    (OFF_S2S  + (size_t)NB*4)             // int2 (perm, wneg) 256 KB
#define OFF_CT16  (OFF_PK   + (size_t)NB*8)             // double [B][256][2][72] 2.36 MB
#define OFF_CTS   (OFF_CT16 + (size_t)BB*NC16*2*CH*8)   // double [B][257][2][72] 2.37 MB
#define OFF_PRANK (OFF_CTS  + (size_t)BB*(NC16+1)*2*CH*8) // u16 [32][B][4096]  2 MB

// monotone float->u32 map (IEEE total order for non-NaN)
__device__ __forceinline__ unsigned int fkey(float f) {
  unsigned int u = __float_as_uint(f);
  return (u & 0x80000000u) ? ~u : (u | 0x80000000u);
}

// ---------------- Kernel A: h = x @ W^T ; s1 = h.a1 ; s2 = h.a2 ----------------
__global__ __launch_bounds__(256) void gat_kA(const float* __restrict__ x,
                                              const float* __restrict__ W,
                                              const float* __restrict__ a,
                                              float* __restrict__ h,
                                              float* __restrict__ s1,
                                              float* __restrict__ s2) {
  __shared__ float xs[64][FF];
  const int tid  = threadIdx.x;
  const int lane = tid & 63;
  const int wave = tid >> 6;
  const long long rowbase = (long long)blockIdx.x * 64;

  const float4* x4  = (const float4*)(x + rowbase * FF);
  float4*       xs4 = (float4*)&xs[0][0];
#pragma unroll
  for (int i = 0; i < 8; ++i) xs4[tid + i * 256] = x4[tid + i * 256];

  float4 wreg[32];
  const float4* W4 = (const float4*)(W + lane * FF);
#pragma unroll
  for (int j = 0; j < 32; ++j) wreg[j] = W4[j];
  const float a1d = a[lane];
  const float a2d = a[DD + lane];
  __syncthreads();

  for (int r = wave * 16; r < wave * 16 + 16; ++r) {
    const float4* xr = (const float4*)&xs[r][0];
    float4 acc = {0.f, 0.f, 0.f, 0.f};
#pragma unroll
    for (int j = 0; j < 32; ++j) {
      float4 xv = xr[j];
      acc.x += xv.x * wreg[j].x;
      acc.y += xv.y * wreg[j].y;
      acc.z += xv.z * wreg[j].z;
      acc.w += xv.w * wreg[j].w;
    }
    float hd = (acc.x + acc.y) + (acc.z + acc.w);
    const long long row = rowbase + r;
    h[row * DD + lane] = hd;

    float p1 = hd * a1d, p2 = hd * a2d;
#pragma unroll
    for (int o = 32; o; o >>= 1) { p1 += __shfl_xor(p1, o); p2 += __shfl_xor(p2, o); }
    if (lane == 0) { s1[row] = p1; s2[row] = p2; }
  }
}

// ---------------- Kernel B1: partial ranks, register-blocked ----------------
__global__ __launch_bounds__(256) void gat_kB1(const float* __restrict__ s2,
                                               unsigned short* __restrict__ prank) {
  __shared__ unsigned long long ks[CHK];
  const int c = blockIdx.x, b = blockIdx.y, tid = threadIdx.x;
  const float* s2b = s2 + (size_t)b * NN;

  if (tid < CHK) {
    const int ig = c * CHK + tid;
    ks[tid] = ((unsigned long long)fkey(s2b[ig]) << 12) | (unsigned)ig;
  }

  unsigned long long kj[16];
  int rank[16];
#pragma unroll
  for (int t = 0; t < 16; ++t) {
    const int j = tid + 256 * t;
    kj[t] = ((unsigned long long)fkey(s2b[j]) << 12) | (unsigned)j;
    rank[t] = 0;
  }
  __syncthreads();

#pragma unroll 4
  for (int i = 0; i < CHK; ++i) {
    const unsigned long long ki = ks[i];
#pragma unroll
    for (int t = 0; t < 16; ++t) rank[t] += (ki < kj[t]) ? 1 : 0;
  }

  unsigned short* pr = prank + ((size_t)c * BB + b) * NN;
#pragma unroll
  for (int t = 0; t < 16; ++t) pr[tid + 256 * t] = (unsigned short)rank[t];
}

// ---------------- Kernel B2: sum partials, batch max, scatter keys + packed w ---
__global__ __launch_bounds__(256) void gat_kB2(const float* __restrict__ s2,
                                               const unsigned short* __restrict__ prank,
                                               float* __restrict__ s2s,
                                               int2* __restrict__ pk) {
  __shared__ float red[4];
  const int b = blockIdx.y, tid = threadIdx.x;
  const int j = blockIdx.x * 256 + tid;
  const float* s2b = s2 + (size_t)b * NN;

  float mx = -3.4e38f;
  for (int i = tid; i < NN; i += 256) mx = fmaxf(mx, s2b[i]);
#pragma unroll
  for (int o = 32; o; o >>= 1) mx = fmaxf(mx, __shfl_xor(mx, o));
  if ((tid & 63) == 0) red[tid >> 6] = mx;
  __syncthreads();
  mx = fmaxf(fmaxf(red[0], red[1]), fmaxf(red[2], red[3]));

  int rank = 0;
#pragma unroll 8
  for (int c = 0; c < NCH; ++c) rank += prank[((size_t)c * BB + b) * NN + j];

  const float key = s2b[j];
  const float wn = expf(0.2f * (key - mx));   // <= 1; wpos = wn^5
  const size_t o = (size_t)b * NN + rank;
  s2s[o] = key;
  pk[o]  = make_int2(j, __float_as_int(wn));
}

// ---------------- Kernel C: 16-element chunk partial sums, fp64 ----------------
__global__ __launch_bounds__(64) void gat_kC(const float* __restrict__ h,
                                             const int2* __restrict__ pk,
                                             double* __restrict__ CT16) {
  const int c = blockIdx.x, b = blockIdx.y, d = threadIdx.x;
  const int base = b * NN + c * CSZ;
  double ap = 0, an = 0, zp = 0, zn = 0;
#pragma unroll
  for (int s = 0; s < CSZ; ++s) {
    const int2 p = pk[base + s];
    const float hv = h[((size_t)(b * NN + p.x)) * DD + d];
    const float wn = __int_as_float(p.y);
    const float w2 = wn * wn;
    const float wp = w2 * w2 * wn;
    an += (double)wn * hv; ap += (double)wp * hv;
    zn += wn;              zp += wp;
  }
  double* o = CT16 + ((size_t)(b * NC16 + c) * 2) * CH;
  o[0 * CH + d] = an;   // fam0 = negative-branch (wneg)
  o[1 * CH + d] = ap;   // fam1 = positive-branch (wpos)
  if (d == 0) { o[0 * CH + 64] = zn; o[1 * CH + 64] = zp; }
}

// ---------------- Kernel D: exclusive scan CT16 -> CTS, deep unroll -------------
// grid (8 batches, 2 fams) x 128; thread = ch; 16 loads in flight per group
__global__ __launch_bounds__(128) void gat_kD(const double* __restrict__ CT16,
                                              double* __restrict__ CTS) {
  const int b = blockIdx.x, fam = blockIdx.y, ch = threadIdx.x;
  if (ch > 64) return;
  double off = 0;
#pragma unroll 16
  for (int c = 0; c < NC16; ++c) {
    CTS[(((size_t)b * (NC16 + 1) + c) * 2 + fam) * CH + ch] = off;
    off += CT16[(((size_t)b * NC16 + c) * 2 + fam) * CH + ch];
  }
  CTS[(((size_t)b * (NC16 + 1) + NC16) * 2 + fam) * CH + ch] = off;
}

// ---------------- Kernel F: LDS keys + ballot search + masked-unroll refine -----
// grid (256 row-groups, 8 batches) x 256; 16 rows per block, 4 per wave.
__global__ __launch_bounds__(256) void gat_kF(const float* __restrict__ s1,
                                              const float* __restrict__ s2s,
                                              const int2* __restrict__ pk,
                                              const float* __restrict__ h,
                                              const double* __restrict__ CTS,
                                              float* __restrict__ out) {
  __shared__ float key[NN];      // 16 KB
  __shared__ float seglast[64];
  const int b = blockIdx.y;
  const int tid = threadIdx.x, lane = tid & 63, wv = tid >> 6;

  const float4* src = (const float4*)(s2s + (size_t)b * NN);
  float4* dst = (float4*)key;
#pragma unroll
  for (int i = 0; i < 4; ++i) dst[tid + 256 * i] = src[tid + 256 * i];
  __syncthreads();
  if (tid < 64) seglast[tid] = key[tid * 64 + 63];
  __syncthreads();

  const int bNN = b * NN;
  const float c1 = key[NN - 1];
  const double* base0 = CTS + ((size_t)b * (NC16 + 1)) * 2 * CH;
  const double* tt = base0 + (size_t)NC16 * 2 * CH + CH;  // fam1 total row
  const double tot = tt[lane];
  const double Zt  = tt[64];
  const float segl = seglast[lane];

  float s1v[4];
#pragma unroll
  for (int r = 0; r < 4; ++r) s1v[r] = s1[bNN + blockIdx.x * 16 + wv * 4 + r];

#pragma unroll
  for (int r = 0; r < 4; ++r) {
    const int rowl = blockIdx.x * 16 + wv * 4 + r;
    const float s1i = s1v[r];
    const float t = -s1i;

    // 64-ary ballot search: k = #{j : key[j] <= t}
    unsigned long long m1 = __ballot(segl <= t);
    int seg = __popcll(m1); if (seg > 63) seg = 63;
    const float v2 = key[seg * 64 + lane];
    const int k = seg * 64 + __popcll(__ballot(v2 <= t));
    const int c16 = k >> 4, cnt = k & 15;   // refine count in [0,15]
    // note: k==4096 -> c16==256 -> prefix row IS the total row; cnt==0. Correct.

    const double* r0 = base0 + (size_t)c16 * 2 * CH;  // fam0 prefix row
    const double* r1 = r0 + CH;                       // fam1 prefix row
    double pre  = r0[lane];
    double p1v  = r1[lane];
    double Zpre = r0[64];
    double Z1   = r1[64];

    // masked, fully-unrolled refine: 15 independent gathers, mask kills extras
    const int j0 = c16 << 4;
#pragma unroll
    for (int jj = 0; jj < 15; ++jj) {
      int jn = j0 + jj; jn = jn < NN ? jn : NN - 1;   // clamp (mask=0 there)
      const int2 p = pk[bNN + jn];
      const float hv = h[((size_t)(bNN + p.x)) * DD + lane];
      const float msk = (jj < cnt) ? 1.0f : 0.0f;
      const float wn = __int_as_float(p.y) * msk;
      const float w2 = wn * wn;
      const float wp = w2 * w2 * wn * msk;            // wn^5 (masked)
      pre += (double)wn * hv; p1v += (double)wp * hv;
      Zpre += wn;             Z1  += wp;
    }

    const float suf_d = (float)(tot - p1v);
    const float Zsuf  = (float)(Zt - Z1);
    const float z = s1i + c1;
    const float m = z >= 0.f ? z : 0.2f * z;
    const float A  = expf(z - m);
    const float Bn = expf(0.2f * z - m);
    const float num = A * suf_d + Bn * (float)pre;
    const float Z   = A * Zsuf  + Bn * (float)Zpre;
    const float hp  = num / Z;
    out[((size_t)(bNN + rowl)) * DD + lane] = hp > 0.f ? hp : expm1f(hp);
  }
}

extern "C" void kernel_launch(void* const* d_in, const int* in_sizes, int n_in,
                              void* d_out, int out_size, void* d_ws, size_t ws_size,
                              hipStream_t stream) {
  const float* x = (const float*)d_in[0];
  const float* W = (const float*)d_in[1];
  const float* a = (const float*)d_in[2];
  float* out = (float*)d_out;

  char* ws = (char*)d_ws;
  float*  h    = (float*)(ws + OFF_H);
  float*  s1   = (float*)(ws + OFF_S1);
  float*  s2   = (float*)(ws + OFF_S2);
  float*  s2s  = (float*)(ws + OFF_S2S);
  int2*   pk   = (int2*) (ws + OFF_PK);
  double* CT16 = (double*)(ws + OFF_CT16);
  double* CTS  = (double*)(ws + OFF_CTS);
  unsigned short* prank = (unsigned short*)(ws + OFF_PRANK);

  gat_kA<<<NB / 64, 256, 0, stream>>>(x, W, a, h, s1, s2);
  gat_kB1<<<dim3(NCH, BB), 256, 0, stream>>>(s2, prank);
  gat_kB2<<<dim3(NN / 256, BB), 256, 0, stream>>>(s2, prank, s2s, pk);
  gat_kC<<<dim3(NC16, BB), 64, 0, stream>>>(h, pk, CT16);
  gat_kD<<<dim3(BB, 2), 128, 0, stream>>>(CT16, CTS);
  gat_kF<<<dim3(NN / 16, BB), 256, 0, stream>>>(s1, s2s, pk, h, CTS, out);
}